// Round 10
// baseline (50.512 us; speedup 1.0000x reference)
//
#include <hip/hip_runtime.h>
#include <hip/hip_bf16.h>

// InferenceLinear: out[m][n] = sum_k x[m][k] * (q[n][k]*qrange[n][k/256] + qmin[n][k/256])
// M=512, N=2048, K=4096, 16 groups of 256.
// R10: R8 champion loop structure EXACTLY (single-buffer LDS, stage->load->barrier
// ->compute; this ordering keeps prefetch loads live across compute — R9's
// reorder let the compiler sink them, VGPR 56 proved it). One change: atomic
// epilogue into zeroed d_out replaces ws+reduce (R9 evidence: atomics write
// through cleanly, WRITE exactly 33.5MB). Saves reduce kernel + ws round-trip.
// 128x128 tiles, BK=64, KSPLIT=8, XCD decode (kc==XCD), 512 thr (8 waves 2Mx4N).

#define M_T 512
#define N_T 2048
#define K_T 4096
#define NGRP 16
#define BM 128
#define BN 128
#define BK 64
#define OUT_ELEMS (M_T * N_T)

typedef __attribute__((ext_vector_type(8))) short mfrag_t;           // 8 bf16 (4 VGPR)
typedef __attribute__((ext_vector_type(8))) unsigned short u16x8;
typedef __attribute__((ext_vector_type(4))) float f32x4;

__device__ __forceinline__ unsigned short f2bf(float f) {
  union { __hip_bfloat16 h; unsigned short u; } c;
  c.h = __float2bfloat16(f);
  return c.u;
}

template <int KSPLIT, bool XCDSWZ>
__global__ __launch_bounds__(512, 4) void dq_gemm_kernel(
    const float* __restrict__ x, const int* __restrict__ qw,
    const float* __restrict__ qrange, const float* __restrict__ qmin,
    float* __restrict__ out) {
  constexpr int KC = K_T / KSPLIT;
  constexpr int NTC = KC / BK;

  // single-buffered, swizzled [row][slot^(row&7)] storage, 8-elem (16B) slots
  __shared__ __align__(16) unsigned short As[BM * BK];
  __shared__ __align__(16) unsigned short Bs[BN * BK];

  const int tid = threadIdx.x;
  int xt, yt, kc;
  if (XCDSWZ) {
    const int b = blockIdx.x;
    kc = b & 7;                 // XCD id == k-chunk (assumes b%8 round-robin)
    const int slot = b >> 3;    // 0..63
    xt = slot & 15;             // n-tile
    yt = slot >> 4;             // m-tile
  } else {
    const int b = blockIdx.x;
    xt = b & 15;
    yt = (b >> 4) & 3;
    kc = b >> 6;
  }
  const int n0 = xt * BN;
  const int m0 = yt * BM;
  const int kbase = kc * KC;

  // staging mapping: thread -> (row 0..127, 16-elem segment 0..3)
  const int srow = tid >> 2;
  const int sseg = tid & 3;

  const float* xp = x + (size_t)(m0 + srow) * K_T + kbase + sseg * 16;
  const int* qp = qw + (size_t)(n0 + srow) * K_T + kbase + sseg * 16;
  const float* qrp = qrange + (size_t)(n0 + srow) * NGRP;
  const float* qmp = qmin + (size_t)(n0 + srow) * NGRP;

  // compute mapping: 8 waves, 2(M) x 4(N); wave tile 64x32
  const int lane = tid & 63;
  const int wv = tid >> 6;
  const int wm = (wv >> 2) * 64;   // 0,64
  const int wn = (wv & 3) * 32;    // 0,32,64,96
  const int lr = lane & 15;
  const int lq = lane >> 4;

  float4 av[4];
  int4 qv[4];
  float sc, mn;

  // prologue loads (t=0)
  {
    const float* a = xp;
    av[0] = *(const float4*)(a + 0);
    av[1] = *(const float4*)(a + 4);
    av[2] = *(const float4*)(a + 8);
    av[3] = *(const float4*)(a + 12);
    const int4* q = (const int4*)qp;
    qv[0] = q[0]; qv[1] = q[1]; qv[2] = q[2]; qv[3] = q[3];
    sc = qrp[kc * (KC / 256)];
    mn = qmp[kc * (KC / 256)];
  }

  f32x4 acc[4][2] = {};

  const int rx7 = srow & 7;
  const int abase = srow * BK;
  const int wslot0 = ((sseg * 2) ^ rx7) << 3;
  const int wslot1 = ((sseg * 2 + 1) ^ rx7) << 3;
  const int rxl = lr & 7;  // read-side xor (row&7 == lr&7: wm,wn,f*16 mult of 8)

  for (int t = 0; t < NTC; ++t) {
    if (t > 0) __syncthreads();  // previous compute done before LDS overwrite

    // ---- stage regs -> LDS (convert to bf16 / dequant) ----
    {
      u16x8 pa0, pa1, pb0, pb1;
      pa0[0] = f2bf(av[0].x); pa0[1] = f2bf(av[0].y); pa0[2] = f2bf(av[0].z); pa0[3] = f2bf(av[0].w);
      pa0[4] = f2bf(av[1].x); pa0[5] = f2bf(av[1].y); pa0[6] = f2bf(av[1].z); pa0[7] = f2bf(av[1].w);
      pa1[0] = f2bf(av[2].x); pa1[1] = f2bf(av[2].y); pa1[2] = f2bf(av[2].z); pa1[3] = f2bf(av[2].w);
      pa1[4] = f2bf(av[3].x); pa1[5] = f2bf(av[3].y); pa1[6] = f2bf(av[3].z); pa1[7] = f2bf(av[3].w);
      pb0[0] = f2bf((float)qv[0].x * sc + mn); pb0[1] = f2bf((float)qv[0].y * sc + mn);
      pb0[2] = f2bf((float)qv[0].z * sc + mn); pb0[3] = f2bf((float)qv[0].w * sc + mn);
      pb0[4] = f2bf((float)qv[1].x * sc + mn); pb0[5] = f2bf((float)qv[1].y * sc + mn);
      pb0[6] = f2bf((float)qv[1].z * sc + mn); pb0[7] = f2bf((float)qv[1].w * sc + mn);
      pb1[0] = f2bf((float)qv[2].x * sc + mn); pb1[1] = f2bf((float)qv[2].y * sc + mn);
      pb1[2] = f2bf((float)qv[2].z * sc + mn); pb1[3] = f2bf((float)qv[2].w * sc + mn);
      pb1[4] = f2bf((float)qv[3].x * sc + mn); pb1[5] = f2bf((float)qv[3].y * sc + mn);
      pb1[6] = f2bf((float)qv[3].z * sc + mn); pb1[7] = f2bf((float)qv[3].w * sc + mn);
      *(u16x8*)&As[abase + wslot0] = pa0;
      *(u16x8*)&As[abase + wslot1] = pa1;
      *(u16x8*)&Bs[abase + wslot0] = pb0;
      *(u16x8*)&Bs[abase + wslot1] = pb1;
    }

    // ---- issue next tile's global loads (complete during compute phase) ----
    if (t + 1 < NTC) {
      const float* a = xp + (size_t)(t + 1) * BK;
      av[0] = *(const float4*)(a + 0);
      av[1] = *(const float4*)(a + 4);
      av[2] = *(const float4*)(a + 8);
      av[3] = *(const float4*)(a + 12);
      const int4* q = (const int4*)(qp + (size_t)(t + 1) * BK);
      qv[0] = q[0]; qv[1] = q[1]; qv[2] = q[2]; qv[3] = q[3];
      const int g = kc * (KC / 256) + ((t + 1) >> 2);  // group = 4 tiles of 64
      sc = qrp[g];
      mn = qmp[g];
    }

    __syncthreads();

    // ---- compute tile t: 2 K-substeps of 32; wave = 4x2 fragments ----
#pragma unroll
    for (int kk = 0; kk < 2; ++kk) {
      const int so = ((kk * 4 + lq) ^ rxl) << 3;
      mfrag_t af[4], bf[2];
#pragma unroll
      for (int fm = 0; fm < 4; ++fm)
        af[fm] = *(const mfrag_t*)&As[(wm + fm * 16 + lr) * BK + so];
#pragma unroll
      for (int fn = 0; fn < 2; ++fn)
        bf[fn] = *(const mfrag_t*)&Bs[(wn + fn * 16 + lr) * BK + so];
#pragma unroll
      for (int fm = 0; fm < 4; ++fm)
#pragma unroll
        for (int fn = 0; fn < 2; ++fn)
          acc[fm][fn] = __builtin_amdgcn_mfma_f32_16x16x32_bf16(af[fm], bf[fn], acc[fm][fn], 0, 0, 0);
    }
  }

  // ---- epilogue: atomicAdd partials into zeroed out ----
  // C/D layout col=lane&15, row=(lane>>4)*4+reg (measured m89/m91)
#pragma unroll
  for (int fm = 0; fm < 4; ++fm) {
#pragma unroll
    for (int fn = 0; fn < 2; ++fn) {
      const int r0 = m0 + wm + fm * 16 + lq * 4;
      const int c = n0 + wn + fn * 16 + lr;
      float* op = out + (size_t)r0 * N_T + c;
      atomicAdd(&op[0 * (size_t)N_T], acc[fm][fn][0]);
      atomicAdd(&op[1 * (size_t)N_T], acc[fm][fn][1]);
      atomicAdd(&op[2 * (size_t)N_T], acc[fm][fn][2]);
      atomicAdd(&op[3 * (size_t)N_T], acc[fm][fn][3]);
    }
  }
}

extern "C" void kernel_launch(void* const* d_in, const int* in_sizes, int n_in,
                              void* d_out, int out_size, void* d_ws, size_t ws_size,
                              hipStream_t stream) {
  const float* x = (const float*)d_in[0];
  const int* qw = (const int*)d_in[1];
  const float* qr = (const float*)d_in[2];
  const float* qm = (const float*)d_in[3];
  float* out = (float*)d_out;

  constexpr int KS = 8;
  hipMemsetAsync(out, 0, (size_t)OUT_ELEMS * sizeof(float), stream);
  const int nblk = (N_T / BN) * (M_T / BM) * KS;  // 16*4*8 = 512
  dq_gemm_kernel<KS, true><<<nblk, dim3(512, 1, 1), 0, stream>>>(x, qw, qr, qm, out);
}

// Round 11
// 35.577 us; speedup vs baseline: 1.4198x; 1.4198x over previous
//
#include <hip/hip_runtime.h>
#include <hip/hip_bf16.h>

// InferenceLinear: out[m][n] = sum_k x[m][k] * (q[n][k]*qrange[n][k/256] + qmin[n][k/256])
// M=512, N=2048, K=4096, 16 groups of 256.
// R11: champion = R8 (ws partials + deterministic reduce; atomics proven +20us
// cross-XCD serialization in R9/R10). Added depth-2 register prefetch: two NAMED
// register sets (static indexing, no runtime-indexed arrays -> no scratch),
// loads for t+2 issued when set is consumed -> ~2 compute phases of HBM slack.
// 128x128 tiles, BK=64, KSPLIT=8, XCD decode (kc==XCD), 512 thr (8 waves 2Mx4N,
// wave 64x32 via 4x2 16x16x32 bf16 frags). Single-buffer LDS (16KB x2).

#define M_T 512
#define N_T 2048
#define K_T 4096
#define NGRP 16
#define BM 128
#define BN 128
#define BK 64
#define OUT_ELEMS (M_T * N_T)

typedef __attribute__((ext_vector_type(8))) short mfrag_t;           // 8 bf16 (4 VGPR)
typedef __attribute__((ext_vector_type(8))) unsigned short u16x8;
typedef __attribute__((ext_vector_type(4))) float f32x4;

__device__ __forceinline__ unsigned short f2bf(float f) {
  union { __hip_bfloat16 h; unsigned short u; } c;
  c.h = __float2bfloat16(f);
  return c.u;
}

template <int KSPLIT, bool ATOMIC, bool XCDSWZ>
__global__ __launch_bounds__(512, 4) void dq_gemm_kernel(
    const float* __restrict__ x, const int* __restrict__ qw,
    const float* __restrict__ qrange, const float* __restrict__ qmin,
    float* __restrict__ dst) {
  constexpr int KC = K_T / KSPLIT;
  constexpr int NTC = KC / BK;   // 8 at KSPLIT=8 (even, required by 2-step loop)

  // single-buffered, swizzled [row][slot^(row&7)] storage, 8-elem (16B) slots
  __shared__ __align__(16) unsigned short As[BM * BK];
  __shared__ __align__(16) unsigned short Bs[BN * BK];

  const int tid = threadIdx.x;
  int xt, yt, kc;
  if (XCDSWZ) {
    const int b = blockIdx.x;
    kc = b & 7;                 // XCD id == k-chunk (assumes b%8 round-robin)
    const int slot = b >> 3;
    xt = slot & 15;             // n-tile
    yt = slot >> 4;             // m-tile
  } else {
    const int b = blockIdx.x;
    xt = b & 15;
    yt = (b >> 4) & 3;
    kc = b >> 6;
  }
  const int n0 = xt * BN;
  const int m0 = yt * BM;
  const int kbase = kc * KC;

  // staging mapping: thread -> (row 0..127, 16-elem segment 0..3)
  const int srow = tid >> 2;
  const int sseg = tid & 3;

  const float* xp = x + (size_t)(m0 + srow) * K_T + kbase + sseg * 16;
  const int* qp = qw + (size_t)(n0 + srow) * K_T + kbase + sseg * 16;
  const float* qrp = qrange + (size_t)(n0 + srow) * NGRP;
  const float* qmp = qmin + (size_t)(n0 + srow) * NGRP;

  // compute mapping: 8 waves, 2(M) x 4(N); wave tile 64x32
  const int lane = tid & 63;
  const int wv = tid >> 6;
  const int wm = (wv >> 2) * 64;   // 0,64
  const int wn = (wv & 3) * 32;    // 0,32,64,96
  const int lr = lane & 15;
  const int lq = lane >> 4;

  const int rx7 = srow & 7;
  const int abase = srow * BK;
  const int wslot0 = ((sseg * 2) ^ rx7) << 3;
  const int wslot1 = ((sseg * 2 + 1) ^ rx7) << 3;
  const int rxl = lr & 7;  // read-side xor (row&7 == lr&7: wm,wn,f*16 mult of 8)

  // two named prefetch register sets (depth-2)
  float4 avA[4], avB[4];
  int4 qvA[4], qvB[4];
  float scA, mnA, scB, mnB;

#define LOADSET(AV, QV, SC, MN, T)                                        \
  do {                                                                    \
    if ((T) < NTC) {                                                      \
      const float* a_ = xp + (size_t)(T) * BK;                            \
      AV[0] = *(const float4*)(a_ + 0);                                   \
      AV[1] = *(const float4*)(a_ + 4);                                   \
      AV[2] = *(const float4*)(a_ + 8);                                   \
      AV[3] = *(const float4*)(a_ + 12);                                  \
      const int4* q_ = (const int4*)(qp + (size_t)(T) * BK);              \
      QV[0] = q_[0]; QV[1] = q_[1]; QV[2] = q_[2]; QV[3] = q_[3];         \
      const int g_ = kc * (KC / 256) + ((T) >> 2);                        \
      SC = qrp[g_];                                                       \
      MN = qmp[g_];                                                       \
    }                                                                     \
  } while (0)

#define STAGESET(AV, QV, SC, MN)                                          \
  do {                                                                    \
    u16x8 pa0, pa1, pb0, pb1;                                             \
    pa0[0] = f2bf(AV[0].x); pa0[1] = f2bf(AV[0].y); pa0[2] = f2bf(AV[0].z); pa0[3] = f2bf(AV[0].w); \
    pa0[4] = f2bf(AV[1].x); pa0[5] = f2bf(AV[1].y); pa0[6] = f2bf(AV[1].z); pa0[7] = f2bf(AV[1].w); \
    pa1[0] = f2bf(AV[2].x); pa1[1] = f2bf(AV[2].y); pa1[2] = f2bf(AV[2].z); pa1[3] = f2bf(AV[2].w); \
    pa1[4] = f2bf(AV[3].x); pa1[5] = f2bf(AV[3].y); pa1[6] = f2bf(AV[3].z); pa1[7] = f2bf(AV[3].w); \
    pb0[0] = f2bf((float)QV[0].x * SC + MN); pb0[1] = f2bf((float)QV[0].y * SC + MN); \
    pb0[2] = f2bf((float)QV[0].z * SC + MN); pb0[3] = f2bf((float)QV[0].w * SC + MN); \
    pb0[4] = f2bf((float)QV[1].x * SC + MN); pb0[5] = f2bf((float)QV[1].y * SC + MN); \
    pb0[6] = f2bf((float)QV[1].z * SC + MN); pb0[7] = f2bf((float)QV[1].w * SC + MN); \
    pb1[0] = f2bf((float)QV[2].x * SC + MN); pb1[1] = f2bf((float)QV[2].y * SC + MN); \
    pb1[2] = f2bf((float)QV[2].z * SC + MN); pb1[3] = f2bf((float)QV[2].w * SC + MN); \
    pb1[4] = f2bf((float)QV[3].x * SC + MN); pb1[5] = f2bf((float)QV[3].y * SC + MN); \
    pb1[6] = f2bf((float)QV[3].z * SC + MN); pb1[7] = f2bf((float)QV[3].w * SC + MN); \
    *(u16x8*)&As[abase + wslot0] = pa0;                                   \
    *(u16x8*)&As[abase + wslot1] = pa1;                                   \
    *(u16x8*)&Bs[abase + wslot0] = pb0;                                   \
    *(u16x8*)&Bs[abase + wslot1] = pb1;                                   \
  } while (0)

#define COMPUTE_TILE()                                                    \
  do {                                                                    \
    _Pragma("unroll")                                                     \
    for (int kk = 0; kk < 2; ++kk) {                                      \
      const int so = ((kk * 4 + lq) ^ rxl) << 3;                          \
      mfrag_t af[4], bf[2];                                               \
      _Pragma("unroll")                                                   \
      for (int fm = 0; fm < 4; ++fm)                                      \
        af[fm] = *(const mfrag_t*)&As[(wm + fm * 16 + lr) * BK + so];     \
      _Pragma("unroll")                                                   \
      for (int fn = 0; fn < 2; ++fn)                                      \
        bf[fn] = *(const mfrag_t*)&Bs[(wn + fn * 16 + lr) * BK + so];     \
      _Pragma("unroll")                                                   \
      for (int fm = 0; fm < 4; ++fm)                                      \
        _Pragma("unroll")                                                 \
        for (int fn = 0; fn < 2; ++fn)                                    \
          acc[fm][fn] = __builtin_amdgcn_mfma_f32_16x16x32_bf16(af[fm], bf[fn], acc[fm][fn], 0, 0, 0); \
    }                                                                     \
  } while (0)

  // prologue: t=0 -> set A, t=1 -> set B
  LOADSET(avA, qvA, scA, mnA, 0);
  LOADSET(avB, qvB, scB, mnB, 1);

  f32x4 acc[4][2] = {};

  static_assert(NTC % 2 == 0, "2-step loop needs even NTC");
  for (int tt = 0; tt < NTC; tt += 2) {
    // ---- t = tt (set A) ----
    if (tt > 0) __syncthreads();        // prev compute done before LDS overwrite
    STAGESET(avA, qvA, scA, mnA);       // waits on set-A loads (issued 2 tiles ago)
    LOADSET(avA, qvA, scA, mnA, tt + 2);
    __syncthreads();
    COMPUTE_TILE();

    // ---- t = tt+1 (set B) ----
    __syncthreads();
    STAGESET(avB, qvB, scB, mnB);
    LOADSET(avB, qvB, scB, mnB, tt + 3);
    __syncthreads();
    COMPUTE_TILE();
  }

  // ---- epilogue. C/D layout col=lane&15, row=(lane>>4)*4+reg (m89/m91) ----
  float* base = ATOMIC ? dst : dst + (size_t)kc * OUT_ELEMS;
#pragma unroll
  for (int fm = 0; fm < 4; ++fm) {
#pragma unroll
    for (int fn = 0; fn < 2; ++fn) {
      const int r0 = m0 + wm + fm * 16 + lq * 4;
      const int c = n0 + wn + fn * 16 + lr;
      float* op = base + (size_t)r0 * N_T + c;
      if (ATOMIC) {
        atomicAdd(&op[0 * (size_t)N_T], acc[fm][fn][0]);
        atomicAdd(&op[1 * (size_t)N_T], acc[fm][fn][1]);
        atomicAdd(&op[2 * (size_t)N_T], acc[fm][fn][2]);
        atomicAdd(&op[3 * (size_t)N_T], acc[fm][fn][3]);
      } else {
        op[0 * (size_t)N_T] = acc[fm][fn][0];
        op[1 * (size_t)N_T] = acc[fm][fn][1];
        op[2 * (size_t)N_T] = acc[fm][fn][2];
        op[3 * (size_t)N_T] = acc[fm][fn][3];
      }
    }
  }
#undef LOADSET
#undef STAGESET
#undef COMPUTE_TILE
}

// out[i] = sum_s ws[s*OUT_ELEMS + i], vectorized float4, fixed order (deterministic)
template <int KSPLIT>
__global__ __launch_bounds__(256) void reduce_kernel(const float* __restrict__ ws,
                                                     float* __restrict__ out) {
  const int i4 = blockIdx.x * 256 + threadIdx.x;
  const size_t base = (size_t)i4 * 4;
  float4 a = *(const float4*)(ws + base);
#pragma unroll
  for (int s = 1; s < KSPLIT; ++s) {
    float4 b = *(const float4*)(ws + (size_t)s * OUT_ELEMS + base);
    a.x += b.x; a.y += b.y; a.z += b.z; a.w += b.w;
  }
  *(float4*)(out + base) = a;
}

extern "C" void kernel_launch(void* const* d_in, const int* in_sizes, int n_in,
                              void* d_out, int out_size, void* d_ws, size_t ws_size,
                              hipStream_t stream) {
  const float* x = (const float*)d_in[0];
  const int* qw = (const int*)d_in[1];
  const float* qr = (const float*)d_in[2];
  const float* qm = (const float*)d_in[3];
  float* out = (float*)d_out;
  float* ws = (float*)d_ws;

  constexpr int KS = 8;
  const size_t need = (size_t)KS * OUT_ELEMS * sizeof(float);
  if (ws_size >= need) {
    const int nblk = (N_T / BN) * (M_T / BM) * KS;  // 16*4*8 = 512
    dq_gemm_kernel<KS, false, true><<<nblk, dim3(512, 1, 1), 0, stream>>>(x, qw, qr, qm, ws);
    reduce_kernel<KS><<<OUT_ELEMS / 4 / 256, 256, 0, stream>>>(ws, out);
  } else {
    // fallback: KSPLIT=4, atomics into zeroed out, plain decode
    hipMemsetAsync(out, 0, (size_t)OUT_ELEMS * sizeof(float), stream);
    const int nblk = (N_T / BN) * (M_T / BM) * 4;
    dq_gemm_kernel<4, true, false><<<nblk, dim3(512, 1, 1), 0, stream>>>(x, qw, qr, qm, out);
  }
}

// Round 13
// 35.554 us; speedup vs baseline: 1.4207x; 1.0006x over previous
//
#include <hip/hip_runtime.h>
#include <hip/hip_bf16.h>

// InferenceLinear: out[m][n] = sum_k x[m][k] * (q[n][k]*qrange[n][k/256] + qmin[n][k/256])
// M=512, N=2048, K=4096, 16 groups of 256.
// R12 resubmit (infra failure, no signal). L3->L2 traffic fix: pre-pack pass
// dequants qweight->bf16 W (16.8MB) and casts x->bf16 X (4.2MB) into ws; GEMM
// becomes pure bf16 with per-XCD working set 2.6MB (L2-fit), half re-read bytes,
// zero staging VALU. Pipeline: pack -> gemm (KSPLIT=8, 128x128, ws fp32
// partials) -> reduce.

#define M_T 512
#define N_T 2048
#define K_T 4096
#define NGRP 16
#define BM 128
#define BN 128
#define BK 64
#define OUT_ELEMS (M_T * N_T)
#define W_ELEMS (N_T * K_T)          // 8388608 bf16
#define X_ELEMS (M_T * K_T)          // 2097152 bf16

typedef __attribute__((ext_vector_type(8))) short mfrag_t;           // 8 bf16 (4 VGPR)
typedef __attribute__((ext_vector_type(8))) unsigned short u16x8;
typedef __attribute__((ext_vector_type(4))) float f32x4;

__device__ __forceinline__ unsigned short f2bf(float f) {
  union { __hip_bfloat16 h; unsigned short u; } c;
  c.h = __float2bfloat16(f);
  return c.u;
}

// ---- pass 1: dequant W (int32 q -> bf16) + cast X (fp32 -> bf16) ----
// blocks [0,4096): W groups-of-8; blocks [4096,5120): X groups-of-8.
__global__ __launch_bounds__(256) void pack_kernel(
    const float* __restrict__ x, const int* __restrict__ qw,
    const float* __restrict__ qrange, const float* __restrict__ qmin,
    unsigned short* __restrict__ wsW, unsigned short* __restrict__ wsX) {
  const int bid = blockIdx.x;
  const int tid = threadIdx.x;
  if (bid < (W_ELEMS / 8) / 256) {
    const int gidx = bid * 256 + tid;        // [0, 1048576)
    const int o = gidx >> 9;                 // 512 groups-of-8 per row
    const int k8 = gidx & 511;
    const int g = k8 >> 5;                   // 32 groups-of-8 per quant group
    const float sc = qrange[o * NGRP + g];
    const float mn = qmin[o * NGRP + g];
    const int4* q = (const int4*)(qw + ((size_t)o << 12) + (k8 << 3));
    const int4 q0 = q[0], q1 = q[1];
    u16x8 p;
    p[0] = f2bf((float)q0.x * sc + mn); p[1] = f2bf((float)q0.y * sc + mn);
    p[2] = f2bf((float)q0.z * sc + mn); p[3] = f2bf((float)q0.w * sc + mn);
    p[4] = f2bf((float)q1.x * sc + mn); p[5] = f2bf((float)q1.y * sc + mn);
    p[6] = f2bf((float)q1.z * sc + mn); p[7] = f2bf((float)q1.w * sc + mn);
    *(u16x8*)(wsW + ((size_t)gidx << 3)) = p;
  } else {
    const int gidx = (bid - (W_ELEMS / 8) / 256) * 256 + tid;  // [0, 262144)
    const float4* a = (const float4*)(x + ((size_t)gidx << 3));
    const float4 a0 = a[0], a1 = a[1];
    u16x8 p;
    p[0] = f2bf(a0.x); p[1] = f2bf(a0.y); p[2] = f2bf(a0.z); p[3] = f2bf(a0.w);
    p[4] = f2bf(a1.x); p[5] = f2bf(a1.y); p[6] = f2bf(a1.z); p[7] = f2bf(a1.w);
    *(u16x8*)(wsX + ((size_t)gidx << 3)) = p;
  }
}

// ---- pass 2: bf16 GEMM, R8-proven loop skeleton ----
template <int KSPLIT, bool XCDSWZ>
__global__ __launch_bounds__(512, 4) void dq_gemm_kernel(
    const unsigned short* __restrict__ wsX, const unsigned short* __restrict__ wsW,
    float* __restrict__ dst) {
  constexpr int KC = K_T / KSPLIT;
  constexpr int NTC = KC / BK;

  // single-buffered, swizzled [row][slot^(row&7)] storage, 8-elem (16B) slots
  __shared__ __align__(16) unsigned short As[BM * BK];
  __shared__ __align__(16) unsigned short Bs[BN * BK];

  const int tid = threadIdx.x;
  int xt, yt, kc;
  if (XCDSWZ) {
    const int b = blockIdx.x;
    kc = b & 7;                 // XCD id == k-chunk (assumes b%8 round-robin)
    const int slot = b >> 3;
    xt = slot & 15;             // n-tile
    yt = slot >> 4;             // m-tile
  } else {
    const int b = blockIdx.x;
    xt = b & 15;
    yt = (b >> 4) & 3;
    kc = b >> 6;
  }
  const int n0 = xt * BN;
  const int m0 = yt * BM;
  const int kbase = kc * KC;

  // staging mapping: thread -> (row 0..127, 16-elem segment 0..3)
  const int srow = tid >> 2;
  const int sseg = tid & 3;

  const unsigned short* ap = wsX + (size_t)(m0 + srow) * K_T + kbase + sseg * 16;
  const unsigned short* bp = wsW + (size_t)(n0 + srow) * K_T + kbase + sseg * 16;

  // compute mapping: 8 waves, 2(M) x 4(N); wave tile 64x32
  const int lane = tid & 63;
  const int wv = tid >> 6;
  const int wm = (wv >> 2) * 64;   // 0,64
  const int wn = (wv & 3) * 32;    // 0,32,64,96
  const int lr = lane & 15;
  const int lq = lane >> 4;

  const int rx7 = srow & 7;
  const int abase = srow * BK;
  const int wslot0 = ((sseg * 2) ^ rx7) << 3;
  const int wslot1 = ((sseg * 2 + 1) ^ rx7) << 3;
  const int rxl = lr & 7;  // read-side xor (row&7 == lr&7: wm,wn,f*16 mult of 8)

  u16x8 av0, av1, bv0, bv1;

  // prologue loads (t=0)
  {
    av0 = *(const u16x8*)(ap);
    av1 = *(const u16x8*)(ap + 8);
    bv0 = *(const u16x8*)(bp);
    bv1 = *(const u16x8*)(bp + 8);
  }

  f32x4 acc[4][2] = {};

  for (int t = 0; t < NTC; ++t) {
    if (t > 0) __syncthreads();  // previous compute done before LDS overwrite

    // ---- stage regs -> LDS ----
    *(u16x8*)&As[abase + wslot0] = av0;
    *(u16x8*)&As[abase + wslot1] = av1;
    *(u16x8*)&Bs[abase + wslot0] = bv0;
    *(u16x8*)&Bs[abase + wslot1] = bv1;

    // ---- issue next tile's global loads (complete during compute phase) ----
    if (t + 1 < NTC) {
      const unsigned short* a_ = ap + (size_t)(t + 1) * BK;
      const unsigned short* b_ = bp + (size_t)(t + 1) * BK;
      av0 = *(const u16x8*)(a_);
      av1 = *(const u16x8*)(a_ + 8);
      bv0 = *(const u16x8*)(b_);
      bv1 = *(const u16x8*)(b_ + 8);
    }

    __syncthreads();

    // ---- compute tile t: 2 K-substeps of 32; wave = 4x2 fragments ----
#pragma unroll
    for (int kk = 0; kk < 2; ++kk) {
      const int so = ((kk * 4 + lq) ^ rxl) << 3;
      mfrag_t af[4], bf[2];
#pragma unroll
      for (int fm = 0; fm < 4; ++fm)
        af[fm] = *(const mfrag_t*)&As[(wm + fm * 16 + lr) * BK + so];
#pragma unroll
      for (int fn = 0; fn < 2; ++fn)
        bf[fn] = *(const mfrag_t*)&Bs[(wn + fn * 16 + lr) * BK + so];
#pragma unroll
      for (int fm = 0; fm < 4; ++fm)
#pragma unroll
        for (int fn = 0; fn < 2; ++fn)
          acc[fm][fn] = __builtin_amdgcn_mfma_f32_16x16x32_bf16(af[fm], bf[fn], acc[fm][fn], 0, 0, 0);
    }
  }

  // ---- epilogue: plain stores of partials to ws slice ----
  // C/D layout col=lane&15, row=(lane>>4)*4+reg (measured m89/m91)
  float* base = dst + (size_t)kc * OUT_ELEMS;
#pragma unroll
  for (int fm = 0; fm < 4; ++fm) {
#pragma unroll
    for (int fn = 0; fn < 2; ++fn) {
      const int r0 = m0 + wm + fm * 16 + lq * 4;
      const int c = n0 + wn + fn * 16 + lr;
      float* op = base + (size_t)r0 * N_T + c;
      op[0 * (size_t)N_T] = acc[fm][fn][0];
      op[1 * (size_t)N_T] = acc[fm][fn][1];
      op[2 * (size_t)N_T] = acc[fm][fn][2];
      op[3 * (size_t)N_T] = acc[fm][fn][3];
    }
  }
}

// ---- pass 3: out[i] = sum_s partials[s][i], deterministic order ----
template <int KSPLIT>
__global__ __launch_bounds__(256) void reduce_kernel(const float* __restrict__ ws,
                                                     float* __restrict__ out) {
  const int i4 = blockIdx.x * 256 + threadIdx.x;
  const size_t base = (size_t)i4 * 4;
  float4 a = *(const float4*)(ws + base);
#pragma unroll
  for (int s = 1; s < KSPLIT; ++s) {
    float4 b = *(const float4*)(ws + (size_t)s * OUT_ELEMS + base);
    a.x += b.x; a.y += b.y; a.z += b.z; a.w += b.w;
  }
  *(float4*)(out + base) = a;
}

// ---- fallback only (never expected to run): naive dot per output elem ----
__global__ void naive_kernel(const float* __restrict__ x, const int* __restrict__ qw,
                             const float* __restrict__ qrange, const float* __restrict__ qmin,
                             float* __restrict__ out) {
  const int idx = blockIdx.x * 256 + threadIdx.x;
  if (idx >= OUT_ELEMS) return;
  const int m = idx / N_T, n = idx % N_T;
  float s = 0.f;
  for (int g = 0; g < NGRP; ++g) {
    const float sc = qrange[n * NGRP + g], mn = qmin[n * NGRP + g];
    float d = 0.f, xs = 0.f;
    for (int k = g * 256; k < (g + 1) * 256; ++k) {
      d += x[(size_t)m * K_T + k] * (float)qw[(size_t)n * K_T + k];
      xs += x[(size_t)m * K_T + k];
    }
    s += d * sc + xs * mn;
  }
  out[idx] = s;
}

extern "C" void kernel_launch(void* const* d_in, const int* in_sizes, int n_in,
                              void* d_out, int out_size, void* d_ws, size_t ws_size,
                              hipStream_t stream) {
  const float* x = (const float*)d_in[0];
  const int* qw = (const int*)d_in[1];
  const float* qr = (const float*)d_in[2];
  const float* qm = (const float*)d_in[3];
  float* out = (float*)d_out;

  constexpr int KS = 8;
  unsigned short* wsW = (unsigned short*)d_ws;
  unsigned short* wsX = wsW + W_ELEMS;
  float* partials = (float*)(wsX + X_ELEMS);
  const size_t need = (size_t)W_ELEMS * 2 + (size_t)X_ELEMS * 2 +
                      (size_t)KS * OUT_ELEMS * sizeof(float);
  if (ws_size >= need) {
    const int packblk = (W_ELEMS / 8) / 256 + (X_ELEMS / 8) / 256;  // 4096+1024
    pack_kernel<<<packblk, 256, 0, stream>>>(x, qw, qr, qm, wsW, wsX);
    const int nblk = (N_T / BN) * (M_T / BM) * KS;  // 512
    dq_gemm_kernel<KS, true><<<nblk, dim3(512, 1, 1), 0, stream>>>(wsX, wsW, partials);
    reduce_kernel<KS><<<OUT_ELEMS / 4 / 256, 256, 0, stream>>>(partials, out);
  } else {
    naive_kernel<<<(OUT_ELEMS + 255) / 256, 256, 0, stream>>>(x, qw, qr, qm, out);
  }
}

// Round 14
// 35.441 us; speedup vs baseline: 1.4252x; 1.0032x over previous
//
#include <hip/hip_runtime.h>
#include <hip/hip_bf16.h>

// InferenceLinear: out[m][n] = sum_k x[m][k] * (q[n][k]*qrange[n][k/256] + qmin[n][k/256])
// M=512, N=2048, K=4096, 16 groups of 256.
// R14: R13 pipeline (pack -> bf16 GEMM -> reduce) with GEMM staging switched to
// global_load_lds width=16 (ladder m97 step; m151: +35% vs reg-staging). LDS dest
// linear per wave; source address inverse-swizzled per lane (col16 = (l&7)^(l>>3)),
// matching the read-side slot^(row&7) since row&7 == l>>3. Removes VGPR round-trip
// and ds_writes. Geometry unchanged: 128x128, BK=64, KSPLIT=8, XCD decode, 512 thr.

#define M_T 512
#define N_T 2048
#define K_T 4096
#define NGRP 16
#define BM 128
#define BN 128
#define BK 64
#define OUT_ELEMS (M_T * N_T)
#define W_ELEMS (N_T * K_T)          // 8388608 bf16
#define X_ELEMS (M_T * K_T)          // 2097152 bf16

typedef __attribute__((ext_vector_type(8))) short mfrag_t;           // 8 bf16 (4 VGPR)
typedef __attribute__((ext_vector_type(8))) unsigned short u16x8;
typedef __attribute__((ext_vector_type(4))) float f32x4;

__device__ __forceinline__ unsigned short f2bf(float f) {
  union { __hip_bfloat16 h; unsigned short u; } c;
  c.h = __float2bfloat16(f);
  return c.u;
}

// ---- pass 1: dequant W (int32 q -> bf16) + cast X (fp32 -> bf16) ----
__global__ __launch_bounds__(256) void pack_kernel(
    const float* __restrict__ x, const int* __restrict__ qw,
    const float* __restrict__ qrange, const float* __restrict__ qmin,
    unsigned short* __restrict__ wsW, unsigned short* __restrict__ wsX) {
  const int bid = blockIdx.x;
  const int tid = threadIdx.x;
  if (bid < (W_ELEMS / 8) / 256) {
    const int gidx = bid * 256 + tid;        // [0, 1048576)
    const int o = gidx >> 9;                 // 512 groups-of-8 per row
    const int k8 = gidx & 511;
    const int g = k8 >> 5;                   // 32 groups-of-8 per quant group
    const float sc = qrange[o * NGRP + g];
    const float mn = qmin[o * NGRP + g];
    const int4* q = (const int4*)(qw + ((size_t)o << 12) + (k8 << 3));
    const int4 q0 = q[0], q1 = q[1];
    u16x8 p;
    p[0] = f2bf((float)q0.x * sc + mn); p[1] = f2bf((float)q0.y * sc + mn);
    p[2] = f2bf((float)q0.z * sc + mn); p[3] = f2bf((float)q0.w * sc + mn);
    p[4] = f2bf((float)q1.x * sc + mn); p[5] = f2bf((float)q1.y * sc + mn);
    p[6] = f2bf((float)q1.z * sc + mn); p[7] = f2bf((float)q1.w * sc + mn);
    *(u16x8*)(wsW + ((size_t)gidx << 3)) = p;
  } else {
    const int gidx = (bid - (W_ELEMS / 8) / 256) * 256 + tid;  // [0, 262144)
    const float4* a = (const float4*)(x + ((size_t)gidx << 3));
    const float4 a0 = a[0], a1 = a[1];
    u16x8 p;
    p[0] = f2bf(a0.x); p[1] = f2bf(a0.y); p[2] = f2bf(a0.z); p[3] = f2bf(a0.w);
    p[4] = f2bf(a1.x); p[5] = f2bf(a1.y); p[6] = f2bf(a1.z); p[7] = f2bf(a1.w);
    *(u16x8*)(wsX + ((size_t)gidx << 3)) = p;
  }
}

// ---- pass 2: bf16 GEMM with global_load_lds staging ----
template <int KSPLIT, bool XCDSWZ>
__global__ __launch_bounds__(512, 4) void dq_gemm_kernel(
    const unsigned short* __restrict__ wsX, const unsigned short* __restrict__ wsW,
    float* __restrict__ dst) {
  constexpr int KC = K_T / KSPLIT;
  constexpr int NTC = KC / BK;

  // physical layout: [row][slot^(row&7)], slot = 8-elem (16B) unit; linear fill
  __shared__ __align__(16) unsigned short As[BM * BK];
  __shared__ __align__(16) unsigned short Bs[BN * BK];

  const int tid = threadIdx.x;
  int xt, yt, kc;
  if (XCDSWZ) {
    const int b = blockIdx.x;
    kc = b & 7;                 // XCD id == k-chunk (assumes b%8 round-robin)
    const int slot = b >> 3;
    xt = slot & 15;             // n-tile
    yt = slot >> 4;             // m-tile
  } else {
    const int b = blockIdx.x;
    xt = b & 15;
    yt = (b >> 4) & 3;
    kc = b >> 6;
  }
  const int n0 = xt * BN;
  const int m0 = yt * BM;
  const int kbase = kc * KC;

  // compute mapping: 8 waves, 2(M) x 4(N); wave tile 64x32
  const int lane = tid & 63;
  const int wv = tid >> 6;
  const int wm = (wv >> 2) * 64;   // 0,64
  const int wn = (wv & 3) * 32;    // 0,32,64,96
  const int lr = lane & 15;
  const int lq = lane >> 4;
  const int rxl = lr & 7;  // read-side xor (row&7 == lr&7: wm,wn,f*16 mult of 8)

  // ---- staging mapping for global_load_lds (width 16B = 8 elems/lane) ----
  // wave wv covers rows [wv*16, wv*16+16) in two 1KB chunks (8 rows each).
  // lane l -> row = base_row + (l>>3), phys slot p = l&7.
  // LDS[row][p] must hold logical data[p ^ (row&7)]; row&7 == l>>3, so the
  // per-lane GLOBAL source col16 = (l&7) ^ (l>>3).
  const int swzcol = (((lane & 7) ^ (lane >> 3)) << 3);       // elem offset
  const int r0 = wv * 16 + (lane >> 3);                        // chunk0 row
  const int r1 = r0 + 8;                                       // chunk1 row
  const unsigned short* gA0 = wsX + (size_t)(m0 + r0) * K_T + kbase + swzcol;
  const unsigned short* gA1 = wsX + (size_t)(m0 + r1) * K_T + kbase + swzcol;
  const unsigned short* gB0 = wsW + (size_t)(n0 + r0) * K_T + kbase + swzcol;
  const unsigned short* gB1 = wsW + (size_t)(n0 + r1) * K_T + kbase + swzcol;
  unsigned short* lA0 = &As[wv * 1024];        // elems; 2KB per wave
  unsigned short* lA1 = &As[wv * 1024 + 512];
  unsigned short* lB0 = &Bs[wv * 1024];
  unsigned short* lB1 = &Bs[wv * 1024 + 512];

#define STAGE(T)                                                              \
  do {                                                                        \
    const size_t o_ = (size_t)(T) * BK;                                       \
    __builtin_amdgcn_global_load_lds(                                         \
        (const __attribute__((address_space(1))) void*)(gA0 + o_),            \
        (__attribute__((address_space(3))) void*)lA0, 16, 0, 0);              \
    __builtin_amdgcn_global_load_lds(                                         \
        (const __attribute__((address_space(1))) void*)(gA1 + o_),            \
        (__attribute__((address_space(3))) void*)lA1, 16, 0, 0);              \
    __builtin_amdgcn_global_load_lds(                                         \
        (const __attribute__((address_space(1))) void*)(gB0 + o_),            \
        (__attribute__((address_space(3))) void*)lB0, 16, 0, 0);              \
    __builtin_amdgcn_global_load_lds(                                         \
        (const __attribute__((address_space(1))) void*)(gB1 + o_),            \
        (__attribute__((address_space(3))) void*)lB1, 16, 0, 0);              \
  } while (0)

  f32x4 acc[4][2] = {};

  STAGE(0);
  for (int t = 0; t < NTC; ++t) {
    __syncthreads();  // drains vmcnt(0): staged tile visible to all waves

    // ---- compute tile t: 2 K-substeps of 32; wave = 4x2 fragments ----
#pragma unroll
    for (int kk = 0; kk < 2; ++kk) {
      const int so = ((kk * 4 + lq) ^ rxl) << 3;
      mfrag_t af[4], bf[2];
#pragma unroll
      for (int fm = 0; fm < 4; ++fm)
        af[fm] = *(const mfrag_t*)&As[(wm + fm * 16 + lr) * BK + so];
#pragma unroll
      for (int fn = 0; fn < 2; ++fn)
        bf[fn] = *(const mfrag_t*)&Bs[(wn + fn * 16 + lr) * BK + so];
#pragma unroll
      for (int fm = 0; fm < 4; ++fm)
#pragma unroll
        for (int fn = 0; fn < 2; ++fn)
          acc[fm][fn] = __builtin_amdgcn_mfma_f32_16x16x32_bf16(af[fm], bf[fn], acc[fm][fn], 0, 0, 0);
    }

    if (t + 1 < NTC) {
      __syncthreads();  // all waves done reading before overwrite
      STAGE(t + 1);
    }
  }
#undef STAGE

  // ---- epilogue: plain stores of partials to ws slice ----
  // C/D layout col=lane&15, row=(lane>>4)*4+reg (measured m89/m91)
  float* base = dst + (size_t)kc * OUT_ELEMS;
#pragma unroll
  for (int fm = 0; fm < 4; ++fm) {
#pragma unroll
    for (int fn = 0; fn < 2; ++fn) {
      const int rr = m0 + wm + fm * 16 + lq * 4;
      const int c = n0 + wn + fn * 16 + lr;
      float* op = base + (size_t)rr * N_T + c;
      op[0 * (size_t)N_T] = acc[fm][fn][0];
      op[1 * (size_t)N_T] = acc[fm][fn][1];
      op[2 * (size_t)N_T] = acc[fm][fn][2];
      op[3 * (size_t)N_T] = acc[fm][fn][3];
    }
  }
}

// ---- pass 3: out[i] = sum_s partials[s][i], deterministic order ----
template <int KSPLIT>
__global__ __launch_bounds__(256) void reduce_kernel(const float* __restrict__ ws,
                                                     float* __restrict__ out) {
  const int i4 = blockIdx.x * 256 + threadIdx.x;
  const size_t base = (size_t)i4 * 4;
  float4 a = *(const float4*)(ws + base);
#pragma unroll
  for (int s = 1; s < KSPLIT; ++s) {
    float4 b = *(const float4*)(ws + (size_t)s * OUT_ELEMS + base);
    a.x += b.x; a.y += b.y; a.z += b.z; a.w += b.w;
  }
  *(float4*)(out + base) = a;
}

// ---- fallback only (never expected to run): naive dot per output elem ----
__global__ void naive_kernel(const float* __restrict__ x, const int* __restrict__ qw,
                             const float* __restrict__ qrange, const float* __restrict__ qmin,
                             float* __restrict__ out) {
  const int idx = blockIdx.x * 256 + threadIdx.x;
  if (idx >= OUT_ELEMS) return;
  const int m = idx / N_T, n = idx % N_T;
  float s = 0.f;
  for (int g = 0; g < NGRP; ++g) {
    const float sc = qrange[n * NGRP + g], mn = qmin[n * NGRP + g];
    float d = 0.f, xs = 0.f;
    for (int k = g * 256; k < (g + 1) * 256; ++k) {
      d += x[(size_t)m * K_T + k] * (float)qw[(size_t)n * K_T + k];
      xs += x[(size_t)m * K_T + k];
    }
    s += d * sc + xs * mn;
  }
  out[idx] = s;
}

extern "C" void kernel_launch(void* const* d_in, const int* in_sizes, int n_in,
                              void* d_out, int out_size, void* d_ws, size_t ws_size,
                              hipStream_t stream) {
  const float* x = (const float*)d_in[0];
  const int* qw = (const int*)d_in[1];
  const float* qr = (const float*)d_in[2];
  const float* qm = (const float*)d_in[3];
  float* out = (float*)d_out;

  constexpr int KS = 8;
  unsigned short* wsW = (unsigned short*)d_ws;
  unsigned short* wsX = wsW + W_ELEMS;
  float* partials = (float*)(wsX + X_ELEMS);
  const size_t need = (size_t)W_ELEMS * 2 + (size_t)X_ELEMS * 2 +
                      (size_t)KS * OUT_ELEMS * sizeof(float);
  if (ws_size >= need) {
    const int packblk = (W_ELEMS / 8) / 256 + (X_ELEMS / 8) / 256;  // 4096+1024
    pack_kernel<<<packblk, 256, 0, stream>>>(x, qw, qr, qm, wsW, wsX);
    const int nblk = (N_T / BN) * (M_T / BM) * KS;  // 512
    dq_gemm_kernel<KS, true><<<nblk, dim3(512, 1, 1), 0, stream>>>(wsX, wsW, partials);
    reduce_kernel<KS><<<OUT_ELEMS / 4 / 256, 256, 0, stream>>>(partials, out);
  } else {
    naive_kernel<<<(OUT_ELEMS + 255) / 256, 256, 0, stream>>>(x, qw, qr, qm, out);
  }
}